// Round 1
// baseline (1651.362 us; speedup 1.0000x reference)
//
#include <hip/hip_runtime.h>
#include <stdint.h>

#define DEV __device__ __forceinline__

typedef __attribute__((ext_vector_type(8))) short short8;
typedef __attribute__((ext_vector_type(4))) float f32x4;

static constexpr int NE   = 256;   // encoder rows = B*S_ENC
static constexpr int ND   = 960;   // decoder rows = 15*B*16
static constexpr int NSEQ = 60;    // 15*B
static constexpr float INVSQ = 0.044194173824159216f; // 1/sqrt(512)
static constexpr float LNEPS = 1e-5f;

DEV float bfu2f(unsigned short u){ return __uint_as_float(((uint32_t)u)<<16); }
DEV unsigned short f2bfu(float f){
  uint32_t x = __float_as_uint(f);
  x += 0x7fffu + ((x>>16)&1u);
  return (unsigned short)(x>>16);
}

DEV float posval(int s, int i){
  // 10000^(-2*floor(i/2)/512): even dims sin, odd dims cos
  const float c = -0.035977892078031968f; // -2*ln(10000)/512
  float x = (float)s * expf(c * (float)(i>>1));
  return (i & 1) ? cosf(x) : sinf(x);
}

DEV float dot512(const unsigned short* __restrict__ a, const unsigned short* __restrict__ b){
  float s = 0.f;
  #pragma unroll 4
  for (int i=0;i<512;i+=8){
    ushort4 a0 = *(const ushort4*)(a+i);
    ushort4 a1 = *(const ushort4*)(a+i+4);
    ushort4 b0 = *(const ushort4*)(b+i);
    ushort4 b1 = *(const ushort4*)(b+i+4);
    s += bfu2f(a0.x)*bfu2f(b0.x) + bfu2f(a0.y)*bfu2f(b0.y)
       + bfu2f(a0.z)*bfu2f(b0.z) + bfu2f(a0.w)*bfu2f(b0.w);
    s += bfu2f(a1.x)*bfu2f(b1.x) + bfu2f(a1.y)*bfu2f(b1.y)
       + bfu2f(a1.z)*bfu2f(b1.z) + bfu2f(a1.w)*bfu2f(b1.w);
  }
  return s;
}

// ---------------- transpose + fp32->bf16 convert ----------------
// src: [z][R][C] f32 row-major; dst slab z at (z%zdiv)*dslab1+(z/zdiv)*dslab2, layout [C][R] bf16
__global__ __launch_bounds__(256) void k_transcvt(const float* __restrict__ src,
    unsigned short* __restrict__ dst, int R, int C, long dslab1, long dslab2, int zdiv){
  __shared__ float tile[32][33];
  int z = blockIdx.z;
  const float* s = src + (size_t)z*R*C;
  unsigned short* d = dst + (size_t)(z%zdiv)*dslab1 + (size_t)(z/zdiv)*dslab2;
  int c0 = blockIdx.x*32, r0 = blockIdx.y*32;
  int tx = threadIdx.x, ty = threadIdx.y;
  #pragma unroll
  for (int i=ty;i<32;i+=8) tile[i][tx] = s[(size_t)(r0+i)*C + (c0+tx)];
  __syncthreads();
  #pragma unroll
  for (int i=ty;i<32;i+=8) d[(size_t)(c0+i)*R + (r0+tx)] = f2bfu(tile[tx][i]);
}

// ---------------- generic bf16 MFMA GEMM ----------------
// C[M,N] = (A[M,K] @ B[K,N] + bias)*scale ; BT is B transposed: [N,K] row-major
// flags: 1 = relu, 2 = f32 output (else bf16)
// batched via blockIdx.z: offset = (z%zdiv)*s?1 + (z/zdiv)*s?2  (A/B in elements, C in bytes)
#define MFMA_KSPLIT 0
__global__ __launch_bounds__(256) void k_gemm(
    const unsigned short* __restrict__ A, long lda,
    const unsigned short* __restrict__ BT, long ldb,
    const float* __restrict__ bias,
    void* __restrict__ Cout, long ldc,
    int M, int N, int K, float scale, int flags,
    int zdiv, long sA1, long sA2, long sB1, long sB2, long sC1, long sC2)
{
  int z = blockIdx.z;
  int zm = z % zdiv, zd = z / zdiv;
  const unsigned short* Ap = A  + zm*sA1 + zd*sA2;
  const unsigned short* Bp = BT + zm*sB1 + zd*sB2;
  char* Cb = (char*)Cout + zm*sC1 + zd*sC2;

  int n0 = blockIdx.x*64, m0 = blockIdx.y*64;
  __shared__ __align__(16) unsigned short As[64][40];
  __shared__ __align__(16) unsigned short Bs[64][40];
  int tid = threadIdx.x;
  int w = tid>>6, l = tid&63;
  int lr = tid>>2, lc = (tid&3)*8;
  f32x4 acc0={0.f,0.f,0.f,0.f}, acc1=acc0, acc2=acc0, acc3=acc0;

  for (int kt=0; kt<K; kt+=32){
    short8 av = {0,0,0,0,0,0,0,0};
    if (m0+lr < M) av = *(const short8*)(Ap + (size_t)(m0+lr)*lda + kt + lc);
    short8 bv = *(const short8*)(Bp + (size_t)(n0+lr)*ldb + kt + lc);
    *(short8*)&As[lr][lc] = av;
    *(short8*)&Bs[lr][lc] = bv;
    __syncthreads();
#if !MFMA_KSPLIT
    short8 af = *(const short8*)&As[(w<<4)+(l&15)][(l>>4)<<3];
    short8 b0 = *(const short8*)&Bs[(l&15)     ][(l>>4)<<3];
    short8 b1 = *(const short8*)&Bs[16+(l&15)  ][(l>>4)<<3];
    short8 b2 = *(const short8*)&Bs[32+(l&15)  ][(l>>4)<<3];
    short8 b3 = *(const short8*)&Bs[48+(l&15)  ][(l>>4)<<3];
#else
    // fallback: split-K-halves fragment layout
    short8 af, b0, b1, b2, b3;
    {
      int kl = (l>>4)<<2;
      const unsigned short* ar = &As[(w<<4)+(l&15)][0];
      #pragma unroll
      for (int j=0;j<4;j++){ af[j]=ar[kl+j]; af[4+j]=ar[16+kl+j]; }
      const unsigned short* r0_=&Bs[(l&15)][0]; const unsigned short* r1_=&Bs[16+(l&15)][0];
      const unsigned short* r2_=&Bs[32+(l&15)][0]; const unsigned short* r3_=&Bs[48+(l&15)][0];
      #pragma unroll
      for (int j=0;j<4;j++){
        b0[j]=r0_[kl+j]; b0[4+j]=r0_[16+kl+j];
        b1[j]=r1_[kl+j]; b1[4+j]=r1_[16+kl+j];
        b2[j]=r2_[kl+j]; b2[4+j]=r2_[16+kl+j];
        b3[j]=r3_[kl+j]; b3[4+j]=r3_[16+kl+j];
      }
    }
#endif
    acc0 = __builtin_amdgcn_mfma_f32_16x16x32_bf16(af, b0, acc0, 0,0,0);
    acc1 = __builtin_amdgcn_mfma_f32_16x16x32_bf16(af, b1, acc1, 0,0,0);
    acc2 = __builtin_amdgcn_mfma_f32_16x16x32_bf16(af, b2, acc2, 0,0,0);
    acc3 = __builtin_amdgcn_mfma_f32_16x16x32_bf16(af, b3, acc3, 0,0,0);
    __syncthreads();
  }

  int rbase = m0 + (w<<4) + ((l>>4)<<2);
  int cb = n0 + (l&15);
  f32x4 accs[4] = {acc0, acc1, acc2, acc3};
  #pragma unroll
  for (int j=0;j<4;j++){
    int n = cb + (j<<4);
    float bb = bias ? bias[n] : 0.f;
    #pragma unroll
    for (int r=0;r<4;r++){
      int m = rbase + r;
      if (m < M){
        float v = (accs[j][r] + bb) * scale;
        if (flags & 1) v = fmaxf(v, 0.f);
        if (flags & 2) ((float*)Cb)[(size_t)m*ldc + n] = v;
        else ((unsigned short*)Cb)[(size_t)m*ldc + n] = f2bfu(v);
      }
    }
  }
}

// ---------------- LayerNorm (optional residual) ----------------
__global__ __launch_bounds__(256) void k_ln(const unsigned short* __restrict__ X,
    const unsigned short* __restrict__ Rr,
    const float* __restrict__ g, const float* __restrict__ bta,
    unsigned short* __restrict__ out){
  int row = blockIdx.x;
  const unsigned short* x = X + (size_t)row*512;
  int tid = threadIdx.x;
  int i0 = tid*2;
  float a0 = bfu2f(x[i0]), a1 = bfu2f(x[i0+1]);
  if (Rr){ const unsigned short* r = Rr + (size_t)row*512; a0 += bfu2f(r[i0]); a1 += bfu2f(r[i0+1]); }
  float s = a0+a1, s2 = a0*a0 + a1*a1;
  #pragma unroll
  for (int o=32;o>0;o>>=1){ s += __shfl_down(s,o); s2 += __shfl_down(s2,o); }
  __shared__ float red[10];
  int w = tid>>6, lane = tid&63;
  if (lane==0){ red[w]=s; red[4+w]=s2; }
  __syncthreads();
  if (tid==0){
    float S=red[0]+red[1]+red[2]+red[3], S2=red[4]+red[5]+red[6]+red[7];
    float mu = S*(1.f/512.f);
    float var = S2*(1.f/512.f) - mu*mu;
    red[8]=mu; red[9]=rsqrtf(var+LNEPS);
  }
  __syncthreads();
  float mu=red[8], inv=red[9];
  out[(size_t)row*512 + i0  ] = f2bfu((a0-mu)*inv*g[i0  ]+bta[i0  ]);
  out[(size_t)row*512 + i0+1] = f2bfu((a1-mu)*inv*g[i0+1]+bta[i0+1]);
}

// ---------------- softmax over 64 keys (encoder), row per block ----------------
__global__ void k_softmax64(float* __restrict__ S){
  int row = blockIdx.x;
  float* s = S + (size_t)row*64;
  int t = threadIdx.x;
  float v = s[t];
  float m = v;
  #pragma unroll
  for (int o=32;o>0;o>>=1) m = fmaxf(m, __shfl_xor(m, o));
  float e = expf(v-m);
  float sum = e;
  #pragma unroll
  for (int o=32;o>0;o>>=1) sum += __shfl_xor(sum, o);
  s[t] = e/sum;
}

// ---------------- encoder AV: cat[b,s, h*512+e] = sum_k P[z][s][k] * V[b*64+k][h*512+e]
__global__ __launch_bounds__(256) void k_av_enc(const float* __restrict__ S,
    const unsigned short* __restrict__ V, unsigned short* __restrict__ cat){
  int z = blockIdx.x; int b = z>>3, h = z&7;
  __shared__ float p[64][64];
  int tid = threadIdx.x;
  for (int i=tid;i<4096;i+=256) ((float*)p)[i] = S[(size_t)z*4096 + i];
  __syncthreads();
  int e0 = tid*2;
  const unsigned short* vbp = V + (size_t)(b*64)*4096 + h*512 + e0;
  unsigned short* cbp = cat + (size_t)(b*64)*4096 + h*512 + e0;
  for (int q0=0;q0<64;q0+=16){
    float acc[16][2];
    #pragma unroll
    for (int q=0;q<16;q++){acc[q][0]=0.f;acc[q][1]=0.f;}
    for (int k=0;k<64;k++){
      ushort2 vv = *(const ushort2*)(vbp + (size_t)k*4096);
      float v0=bfu2f(vv.x), v1=bfu2f(vv.y);
      #pragma unroll
      for (int q=0;q<16;q++){ float pv = p[q0+q][k]; acc[q][0]+=pv*v0; acc[q][1]+=pv*v1; }
    }
    #pragma unroll
    for (int q=0;q<16;q++){
      ushort2 ov; ov.x=f2bfu(acc[q][0]); ov.y=f2bfu(acc[q][1]);
      *(ushort2*)(cbp + (size_t)(q0+q)*4096) = ov;
    }
  }
}

// ---------------- decoder self-attention (16 pos, keys<=t), fused ----------------
__global__ __launch_bounds__(256) void k_attn_self(const unsigned short* __restrict__ Q,
    const unsigned short* __restrict__ Kk, const unsigned short* __restrict__ V,
    unsigned short* __restrict__ cat){
  int z = blockIdx.x;
  int h = z&7, seq = z>>3, ti = seq>>2, t = ti+1;
  size_t rb = (size_t)seq*16;
  __shared__ float p[16][16];
  int tid = threadIdx.x;
  int q = tid>>4, k = tid&15;
  float dv = 0.f;
  if (k <= t) dv = dot512(Q + (rb+q)*4096 + h*512, Kk + (rb+k)*4096 + h*512) * INVSQ;
  p[q][k] = dv;
  __syncthreads();
  if (tid < 16){
    float m = -1e30f;
    for (int kk=0;kk<=t;kk++) m = fmaxf(m, p[tid][kk]);
    float sum = 0.f;
    for (int kk=0;kk<=t;kk++){ float e = expf(p[tid][kk]-m); p[tid][kk]=e; sum+=e; }
    float inv = 1.f/sum;
    for (int kk=0;kk<16;kk++) p[tid][kk] = (kk<=t) ? p[tid][kk]*inv : 0.f;
  }
  __syncthreads();
  int e0 = tid*2;
  const unsigned short* vbp = V + rb*4096 + h*512 + e0;
  unsigned short* cbp = cat + rb*4096 + h*512 + e0;
  float acc[16][2];
  #pragma unroll
  for (int qq=0;qq<16;qq++){acc[qq][0]=0.f;acc[qq][1]=0.f;}
  for (int kk=0;kk<=t;kk++){
    ushort2 vv = *(const ushort2*)(vbp + (size_t)kk*4096);
    float v0=bfu2f(vv.x), v1=bfu2f(vv.y);
    #pragma unroll
    for (int qq=0;qq<16;qq++){ float pv = p[qq][kk]; acc[qq][0]+=pv*v0; acc[qq][1]+=pv*v1; }
  }
  #pragma unroll
  for (int qq=0;qq<16;qq++){
    ushort2 ov; ov.x=f2bfu(acc[qq][0]); ov.y=f2bfu(acc[qq][1]);
    *(ushort2*)(cbp + (size_t)qq*4096) = ov;
  }
}

// ---------------- decoder cross-attention (16 q, 64 enc keys), fused ----------------
__global__ __launch_bounds__(256) void k_attn_cross(const unsigned short* __restrict__ Qc,
    const unsigned short* __restrict__ Kc, const unsigned short* __restrict__ Vc,
    unsigned short* __restrict__ cat){
  int z = blockIdx.x;
  int h = z&7, seq = z>>3, b = seq&3;
  __shared__ float p[16][64];
  int tid = threadIdx.x;
  #pragma unroll
  for (int i=0;i<4;i++){
    int pid = i*256 + tid; int q = pid>>6, k = pid&63;
    p[q][k] = dot512(Qc + ((size_t)seq*16+q)*4096 + h*512,
                     Kc + ((size_t)b*64+k)*4096 + h*512) * INVSQ;
  }
  __syncthreads();
  if (tid<16){
    float m=-1e30f;
    for (int kk=0;kk<64;kk++) m = fmaxf(m, p[tid][kk]);
    float sum=0.f;
    for (int kk=0;kk<64;kk++){ float e=expf(p[tid][kk]-m); p[tid][kk]=e; sum+=e; }
    float inv=1.f/sum;
    for (int kk=0;kk<64;kk++) p[tid][kk]*=inv;
  }
  __syncthreads();
  int e0 = tid*2;
  const unsigned short* vbp = Vc + (size_t)(b*64)*4096 + h*512 + e0;
  unsigned short* cbp = cat + ((size_t)seq*16)*4096 + h*512 + e0;
  float acc[16][2];
  #pragma unroll
  for (int qq=0;qq<16;qq++){acc[qq][0]=0.f;acc[qq][1]=0.f;}
  for (int kk=0;kk<64;kk++){
    ushort2 vv = *(const ushort2*)(vbp + (size_t)kk*4096);
    float v0=bfu2f(vv.x), v1=bfu2f(vv.y);
    #pragma unroll
    for (int qq=0;qq<16;qq++){ float pv = p[qq][kk]; acc[qq][0]+=pv*v0; acc[qq][1]+=pv*v1; }
  }
  #pragma unroll
  for (int qq=0;qq<16;qq++){
    ushort2 ov; ov.x=f2bfu(acc[qq][0]); ov.y=f2bfu(acc[qq][1]);
    *(ushort2*)(cbp + (size_t)qq*4096) = ov;
  }
}

// ---------------- embeddings ----------------
__global__ __launch_bounds__(256) void k_embed_enc(const int* __restrict__ pieces,
    const float* __restrict__ emb, unsigned short* __restrict__ out){
  int row = blockIdx.x;          // b*64+s
  int s = row & 63;
  int tok = pieces[row];
  for (int e = threadIdx.x; e < 512; e += 256){
    float v = emb[(size_t)tok*512 + e] + posval(s, e);
    out[(size_t)row*512 + e] = f2bfu(v);
  }
}

__global__ __launch_bounds__(256) void k_init_dec(const int* __restrict__ targets,
    const float* __restrict__ zh, unsigned short* __restrict__ out){
  int row = blockIdx.x;          // (ti*4+b)*16 + p
  int p = row & 15, seq = row >> 4;
  int b = seq & 3, ti = seq >> 2, t = ti + 1;
  if (p < t){
    int tok = (p==0) ? 1 : targets[b*16 + p];
    for (int e=threadIdx.x; e<512; e+=256)
      out[(size_t)row*512+e] = f2bfu(zh[(size_t)tok*512+e] + posval(p, e));
  } else {
    for (int e=threadIdx.x; e<512; e+=256) out[(size_t)row*512+e] = 0;
  }
}

__global__ __launch_bounds__(256) void k_gather(const unsigned short* __restrict__ st,
    unsigned short* __restrict__ xf){
  int r = blockIdx.x;            // b*15+ti
  int b = r/15, ti = r%15, t = ti+1;
  int srow = (ti*4+b)*16 + t;
  for (int e=threadIdx.x;e<512;e+=256) xf[(size_t)r*512+e] = st[(size_t)srow*512+e];
}

// ================= host =================
extern "C" void kernel_launch(void* const* d_in, const int* in_sizes, int n_in,
                              void* d_out, int out_size, void* d_ws, size_t ws_size,
                              hipStream_t stream)
{
  (void)in_sizes; (void)n_in; (void)out_size; (void)ws_size;
  const int* pieces  = (const int*)d_in[0];
  const int* targets = (const int*)d_in[1];
  const float* en_emb = (const float*)d_in[2];
  const float* zh_emb = (const float*)d_in[3];
  const float *Wq[3], *bq[3], *Wk[3], *bk[3], *Wv[3], *bv[3], *Wo[3], *bo[3];
  for (int p=0;p<3;p++){
    int base = 4 + p*8;
    Wq[p]=(const float*)d_in[base+0]; bq[p]=(const float*)d_in[base+1];
    Wk[p]=(const float*)d_in[base+2]; bk[p]=(const float*)d_in[base+3];
    Wv[p]=(const float*)d_in[base+4]; bv[p]=(const float*)d_in[base+5];
    Wo[p]=(const float*)d_in[base+6]; bo[p]=(const float*)d_in[base+7];
  }
  const float *ln_g[5], *ln_b[5];
  for (int i=0;i<5;i++){ ln_g[i]=(const float*)d_in[28+2*i]; ln_b[i]=(const float*)d_in[29+2*i]; }
  const float* fW1[2]={(const float*)d_in[38],(const float*)d_in[42]};
  const float* fb1[2]={(const float*)d_in[39],(const float*)d_in[43]};
  const float* fW2[2]={(const float*)d_in[40],(const float*)d_in[44]};
  const float* fb2[2]={(const float*)d_in[41],(const float*)d_in[45]};
  const float* outW=(const float*)d_in[46];
  const float* outb=(const float*)d_in[47];

  char* wsb = (char*)d_ws;
  size_t off = 0;
  auto alloc = [&](size_t bytes)->char*{
    char* pp = wsb + off;
    off = (off + bytes + 255) & ~(size_t)255;
    return pp;
  };
  const size_t HDD  = (size_t)8*512*512;   // per-layer per-proj elems
  const size_t LHDD = 2*HDD;

  unsigned short *wtq[3], *wtk[3], *wtv[3], *wto[3];
  for (int p=0;p<3;p++){
    wtq[p]=(unsigned short*)alloc(LHDD*2);
    wtk[p]=(unsigned short*)alloc(LHDD*2);
    wtv[p]=(unsigned short*)alloc(LHDD*2);
    wto[p]=(unsigned short*)alloc(LHDD*2);       // [L][512][4096]
  }
  unsigned short *wtf1[2], *wtf2[2];
  for (int p=0;p<2;p++){
    wtf1[p]=(unsigned short*)alloc((size_t)2*512*512*2);
    wtf2[p]=(unsigned short*)alloc((size_t)2*512*512*2);
  }
  unsigned short* wtout = (unsigned short*)alloc((size_t)32000*512*2);
  unsigned short* xe   = (unsigned short*)alloc((size_t)NE*512*2);
  unsigned short* est  = (unsigned short*)alloc((size_t)2*NE*512*2);
  unsigned short* qb   = (unsigned short*)alloc((size_t)ND*4096*2);
  unsigned short* kb   = (unsigned short*)alloc((size_t)ND*4096*2);
  unsigned short* vb   = (unsigned short*)alloc((size_t)ND*4096*2);
  unsigned short* qcb  = (unsigned short*)alloc((size_t)ND*4096*2);
  unsigned short* catb = (unsigned short*)alloc((size_t)ND*4096*2);
  unsigned short* kcb  = (unsigned short*)alloc((size_t)2*NE*4096*2);
  unsigned short* vcb  = (unsigned short*)alloc((size_t)2*NE*4096*2);
  float* sbuf          = (float*)alloc((size_t)32*64*64*4);
  unsigned short* dsb  = (unsigned short*)alloc((size_t)ND*512*2);
  unsigned short* t0   = (unsigned short*)alloc((size_t)ND*512*2);
  unsigned short* t1   = (unsigned short*)alloc((size_t)ND*512*2);
  unsigned short* t2   = (unsigned short*)alloc((size_t)ND*512*2);
  unsigned short* t3   = (unsigned short*)alloc((size_t)ND*512*2);
  unsigned short* xfin = (unsigned short*)alloc((size_t)64*512*2);

  dim3 tb(32,8,1);
  // ---- weight conversions (transpose to [N][K] bf16) ----
  for (int p=0;p<3;p++){
    k_transcvt<<<dim3(16,16,16), tb, 0, stream>>>(Wq[p], wtq[p], 512, 512, 512*512, 0, 16);
    k_transcvt<<<dim3(16,16,16), tb, 0, stream>>>(Wk[p], wtk[p], 512, 512, 512*512, 0, 16);
    k_transcvt<<<dim3(16,16,16), tb, 0, stream>>>(Wv[p], wtv[p], 512, 512, 512*512, 0, 16);
    k_transcvt<<<dim3(16,128,2), tb, 0, stream>>>(Wo[p], wto[p], 4096, 512, (long)4096*512, 0, 2);
  }
  for (int p=0;p<2;p++){
    k_transcvt<<<dim3(16,16,2), tb, 0, stream>>>(fW1[p], wtf1[p], 512, 512, 512*512, 0, 2);
    k_transcvt<<<dim3(16,16,2), tb, 0, stream>>>(fW2[p], wtf2[p], 512, 512, 512*512, 0, 2);
  }
  k_transcvt<<<dim3(1000,16,1), tb, 0, stream>>>(outW, wtout, 512, 32000, 0, 0, 1);

  auto gemm = [&](const unsigned short* A, long lda, const unsigned short* BT, long ldb,
                  const float* bias, void* C, long ldc, int M, int N, int K,
                  float scale, int flags, int nz=1, int zdiv=1,
                  long sA1=0, long sA2=0, long sB1=0, long sB2=0, long sC1=0, long sC2=0){
    k_gemm<<<dim3(N/64, (M+63)/64, nz), 256, 0, stream>>>(A, lda, BT, ldb, bias, C, ldc,
        M, N, K, scale, flags, zdiv, sA1, sA2, sB1, sB2, sC1, sC2);
  };

  // ---- encoder ----
  k_embed_enc<<<NE, 256, 0, stream>>>(pieces, en_emb, xe);
  unsigned short* xcur = xe;
  for (int l=0;l<2;l++){
    gemm(xcur, 512, wtq[0]+(size_t)l*HDD, 512, bq[0]+(size_t)l*4096, qb, 4096, NE, 4096, 512, 1.f, 0);
    gemm(xcur, 512, wtk[0]+(size_t)l*HDD, 512, bk[0]+(size_t)l*4096, kb, 4096, NE, 4096, 512, 1.f, 0);
    gemm(xcur, 512, wtv[0]+(size_t)l*HDD, 512, bv[0]+(size_t)l*4096, vb, 4096, NE, 4096, 512, 1.f, 0);
    // scores: batched over (b,h): z = b*8+h
    gemm(qb, 4096, kb, 4096, nullptr, sbuf, 64, 64, 64, 512, INVSQ, 2,
         32, 8, 512, (long)64*4096, 512, (long)64*4096, (long)64*64*4, (long)8*64*64*4);
    k_softmax64<<<2048, 64, 0, stream>>>(sbuf);
    k_av_enc<<<32, 256, 0, stream>>>(sbuf, vb, catb);
    gemm(catb, 4096, wto[0]+(size_t)l*HDD, 4096, bo[0]+(size_t)l*512, t0, 512, NE, 512, 4096, 1.f, 0);
    k_ln<<<NE,256,0,stream>>>(xcur, t0, ln_g[0]+(size_t)l*512, ln_b[0]+(size_t)l*512, t1);
    gemm(t1, 512, wtf1[0]+(size_t)l*512*512, 512, fb1[0]+(size_t)l*512, t0, 512, NE, 512, 512, 1.f, 1);
    gemm(t0, 512, wtf2[0]+(size_t)l*512*512, 512, fb2[0]+(size_t)l*512, t2, 512, NE, 512, 512, 1.f, 0);
    unsigned short* eo = est + (size_t)l*NE*512;
    k_ln<<<NE,256,0,stream>>>(t2, nullptr, ln_g[1]+(size_t)l*512, ln_b[1]+(size_t)l*512, eo);
    xcur = eo;
  }

  // ---- cross K/V (once per layer) ----
  for (int l=0;l<2;l++){
    gemm(est+(size_t)l*NE*512, 512, wtk[2]+(size_t)l*HDD, 512, bk[2]+(size_t)l*4096,
         kcb+(size_t)l*NE*4096, 4096, NE, 4096, 512, 1.f, 0);
    gemm(est+(size_t)l*NE*512, 512, wtv[2]+(size_t)l*HDD, 512, bv[2]+(size_t)l*4096,
         vcb+(size_t)l*NE*4096, 4096, NE, 4096, 512, 1.f, 0);
  }

  // ---- decoder: all 15 steps in parallel (rows = (ti*4+b)*16+p) ----
  k_init_dec<<<ND, 256, 0, stream>>>(targets, zh_emb, dsb);
  for (int l=0;l<2;l++){
    gemm(dsb, 512, wtq[1]+(size_t)l*HDD, 512, bq[1]+(size_t)l*4096, qb, 4096, ND, 4096, 512, 1.f, 0);
    gemm(dsb, 512, wtk[1]+(size_t)l*HDD, 512, bk[1]+(size_t)l*4096, kb, 4096, ND, 4096, 512, 1.f, 0);
    gemm(dsb, 512, wtv[1]+(size_t)l*HDD, 512, bv[1]+(size_t)l*4096, vb, 4096, ND, 4096, 512, 1.f, 0);
    k_attn_self<<<480, 256, 0, stream>>>(qb, kb, vb, catb);
    gemm(catb, 4096, wto[1]+(size_t)l*HDD, 4096, bo[1]+(size_t)l*512, t0, 512, ND, 512, 4096, 1.f, 0);
    k_ln<<<ND,256,0,stream>>>(dsb, t0, ln_g[2]+(size_t)l*512, ln_b[2]+(size_t)l*512, t1);
    gemm(t1, 512, wtq[2]+(size_t)l*HDD, 512, bq[2]+(size_t)l*4096, qcb, 4096, ND, 4096, 512, 1.f, 0);
    k_attn_cross<<<480, 256, 0, stream>>>(qcb, kcb+(size_t)l*NE*4096, vcb+(size_t)l*NE*4096, catb);
    gemm(catb, 4096, wto[2]+(size_t)l*HDD, 4096, bo[2]+(size_t)l*512, t0, 512, ND, 512, 4096, 1.f, 0);
    k_ln<<<ND,256,0,stream>>>(t1, t0, ln_g[3]+(size_t)l*512, ln_b[3]+(size_t)l*512, t2);
    gemm(t2, 512, wtf1[1]+(size_t)l*512*512, 512, fb1[1]+(size_t)l*512, t0, 512, ND, 512, 512, 1.f, 1);
    gemm(t0, 512, wtf2[1]+(size_t)l*512*512, 512, fb2[1]+(size_t)l*512, t3, 512, ND, 512, 512, 1.f, 0);
    k_ln<<<ND,256,0,stream>>>(t3, nullptr, ln_g[4]+(size_t)l*512, ln_b[4]+(size_t)l*512, dsb);
  }

  // ---- readout: position t of step t -> logits ----
  k_gather<<<NSEQ, 256, 0, stream>>>(dsb, xfin);
  gemm(xfin, 512, wtout, 512, outb, d_out, 32000, NSEQ, 32000, 512, 1.f, 2);
}